// Round 8
// baseline (162.706 us; speedup 1.0000x reference)
//
#include <hip/hip_runtime.h>
#include <math.h>

#ifndef M_PI
#define M_PI 3.14159265358979323846
#endif

constexpr int   NMORT  = 4096;        // 16^3 morton cells
constexpr int   NCELL  = 8192;        // 2 tightness classes x NMORT
constexpr int   TSZ    = 64;          // points per tile (= wavefront)
constexpr int   SPLIT  = 32;          // j-tile slices (blockIdx.y)
constexpr float CUT    = 26.4f;       // 24 + log2(norms3); err <= 16384*5.2*2^-24 ~ 5e-3
constexpr float ALOOSE = 4.0f;        // class threshold on A = a*log2e

// y[i,c] = norms[c] * sum_j exp(-(a_j + b_ic)||xi-xj||^2) f_j ; b_i = {a/2, a, 2a}
// u = exp2(-(Ai/2)s), Aw = exp2(-Aj*s) -> w = {Aw u, Aw u^2, Aw u^4}
// Pruning at tile level (class-pure tiles) + per-j wave vote.

__device__ __forceinline__ int expand4(int v) {
    return (v & 1) | ((v & 2) << 2) | ((v & 4) << 4) | ((v & 8) << 6);
}

__device__ __forceinline__ float compA(float rho_, float gam, float C2, float Kttf) {
    const float LOG2E = 1.4426950408889634f;
    const float PI_F  = 3.14159265358979f;
    float r  = rho_ + 1e-8f;
    float sc = PI_F * powf(0.5f * r, 2.0f / 3.0f);
    float xq = (gam / (8.0f * r)) / (Kttf * powf(r, 5.0f / 3.0f));
    return LOG2E * sc * (2.0f + C2 * xq);      // a * log2(e) > 0
}

__device__ __forceinline__ int cellkey(float x, float y, float z, float A) {
    int cx = min(15, max(0, (int)floorf((x + 16.f) * 0.5f)));
    int cy = min(15, max(0, (int)floorf((y + 16.f) * 0.5f)));
    int cz = min(15, max(0, (int)floorf((z + 16.f) * 0.5f)));
    int m  = expand4(cx) | (expand4(cy) << 1) | (expand4(cz) << 2);
    return ((A < ALOOSE) ? NMORT : 0) + m;
}

// K1: single block — cell ids, LDS histogram, LDS scan -> global cursor
__global__ __launch_bounds__(1024)
void k_cells(const float* __restrict__ rho, const float* __restrict__ gamma,
             const float* __restrict__ coords,
             unsigned short* __restrict__ cellid, int* __restrict__ cursor,
             int n, float C2, float Kttf)
{
    __shared__ int hist[NCELL];
    __shared__ int ssum[1024];
    const int t = threadIdx.x;
    for (int c = t; c < NCELL; c += 1024) hist[c] = 0;
    __syncthreads();
    for (int i = t; i < n; i += 1024) {
        float A = compA(rho[i], gamma[i], C2, Kttf);
        int cid = cellkey(coords[3*i], coords[3*i+1], coords[3*i+2], A);
        cellid[i] = (unsigned short)cid;
        atomicAdd(&hist[cid], 1);
    }
    __syncthreads();
    int h[8], s = 0;
    const int base = t * 8;
    #pragma unroll
    for (int k = 0; k < 8; ++k) { h[k] = hist[base + k]; s += h[k]; }
    ssum[t] = s;
    __syncthreads();
    for (int off = 1; off < 1024; off <<= 1) {
        int v = (t >= off) ? ssum[t - off] : 0;
        __syncthreads();
        ssum[t] += v;
        __syncthreads();
    }
    int excl = ssum[t] - s;
    #pragma unroll
    for (int k = 0; k < 8; ++k) { cursor[base + k] = excl; excl += h[k]; }
}

// K2: scatter into sorted order + per-point precompute
__global__ __launch_bounds__(256)
void k_scatter(const float* __restrict__ rho, const float* __restrict__ gamma,
               const float* __restrict__ coords, const float* __restrict__ weights,
               const unsigned short* __restrict__ cellid, int* __restrict__ cursor,
               float4* __restrict__ XYZQ, float2* __restrict__ AF,
               unsigned short* __restrict__ perm, int n, float C2, float Kttf)
{
    int i = blockIdx.x * 256 + threadIdx.x;
    if (i >= n) return;
    int pos = atomicAdd(&cursor[cellid[i]], 1);
    float A = compA(rho[i], gamma[i], C2, Kttf);
    float x = coords[3*i], y = coords[3*i+1], z = coords[3*i+2];
    XYZQ[pos] = make_float4(x, y, z, x*x + y*y + z*z);
    AF[pos]   = make_float2(A, weights[i] * rho[i]);
    perm[pos] = (unsigned short)i;
}

// K3: per-tile bounds {minx,miny,minz,maxx, maxy,maxz, Amin, Lmax}
__global__ __launch_bounds__(64)
void k_bounds(const float4* __restrict__ XYZQ, const float2* __restrict__ AF,
              float* __restrict__ tiles)
{
    int p = blockIdx.x * TSZ + threadIdx.x;
    float4 v = XYZQ[p];
    float2 af = AF[p];
    float lf = log2f(fmaxf(af.y, 1e-30f));
    float mnx=v.x, mny=v.y, mnz=v.z, mxx=v.x, mxy=v.y, mxz=v.z, mA=af.x, mL=lf;
    for (int d = 1; d < 64; d <<= 1) {
        mnx = fminf(mnx, __shfl_xor(mnx, d));
        mny = fminf(mny, __shfl_xor(mny, d));
        mnz = fminf(mnz, __shfl_xor(mnz, d));
        mxx = fmaxf(mxx, __shfl_xor(mxx, d));
        mxy = fmaxf(mxy, __shfl_xor(mxy, d));
        mxz = fmaxf(mxz, __shfl_xor(mxz, d));
        mA  = fminf(mA,  __shfl_xor(mA,  d));
        mL  = fmaxf(mL,  __shfl_xor(mL,  d));
    }
    if (threadIdx.x == 0) {
        float* tb = tiles + blockIdx.x * 8;
        tb[0]=mnx; tb[1]=mny; tb[2]=mnz; tb[3]=mxx;
        tb[4]=mxy; tb[5]=mxz; tb[6]=mA;  tb[7]=mL;
    }
}

// K4: main — tile-level AABB prune + per-j wave-vote exp skip
__global__ __launch_bounds__(256)
void k_main(const float4* __restrict__ XYZQ, const float2* __restrict__ AF,
            const unsigned short* __restrict__ perm, const float* __restrict__ tiles,
            float* __restrict__ out, int nt,
            float n1, float n2, float n3)
{
    const int wave = threadIdx.x >> 6;
    const int lane = threadIdx.x & 63;
    const int it   = blockIdx.x * 4 + wave;
    const int p    = it * TSZ + lane;

    float4 me  = XYZQ[p];
    float2 maf = AF[p];
    const float xi = me.x, yi = me.y, zi = me.z, qi = me.w;
    const float m2 = 0.5f * maf.x;               // Bi = (a_i/2) log2e
    const float mx2 = -2.0f * xi, my2 = -2.0f * yi, mz2 = -2.0f * zi;

    // wave AABB + Bmin
    float mnx=xi, mny=yi, mnz=zi, mxx=xi, mxy=yi, mxz=zi, mB=m2;
    for (int d = 1; d < 64; d <<= 1) {
        mnx = fminf(mnx, __shfl_xor(mnx, d));
        mny = fminf(mny, __shfl_xor(mny, d));
        mnz = fminf(mnz, __shfl_xor(mnz, d));
        mxx = fmaxf(mxx, __shfl_xor(mxx, d));
        mxy = fmaxf(mxy, __shfl_xor(mxy, d));
        mxz = fmaxf(mxz, __shfl_xor(mxz, d));
        mB  = fminf(mB,  __shfl_xor(mB,  d));
    }

    float acc1 = 0.f, acc2 = 0.f, acc3 = 0.f;
    bool any = false;

    const int tps = nt / SPLIT;
    for (int k = 0; k < tps; ++k) {
        int jt = blockIdx.y + k * SPLIT;         // strided -> load balance
        const float* tb = tiles + jt * 8;
        float gx = fmaxf(0.f, fmaxf(tb[0] - mxx, mnx - tb[3]));
        float gy = fmaxf(0.f, fmaxf(tb[1] - mxy, mny - tb[4]));
        float gz = fmaxf(0.f, fmaxf(tb[2] - mxz, mnz - tb[5]));
        float d2 = gx*gx + gy*gy + gz*gz;
        float ctile = CUT + tb[7];
        if (d2 * (tb[6] + mB) > ctile) continue;
        any = true;
        int jb = jt * TSZ;
        #pragma unroll 4
        for (int jj = 0; jj < TSZ; ++jj) {
            float4 J  = XYZQ[jb + jj];           // uniform addr -> s_load
            float2 af = AF[jb + jj];
            float s  = fmaf(J.x, mx2, fmaf(J.y, my2, fmaf(J.z, mz2, J.w + qi)));
            float tA = af.x * s;                 // Aj*s (also the exp arg)
            float m  = fmaf(s, mB, tA);          // (Aj+Bmin)*s
            if (__any(m < ctile)) {
                float Aw = __builtin_amdgcn_exp2f(-tA);
                float u  = __builtin_amdgcn_exp2f(-(m2 * s));
                float u2 = u * u, u4 = u2 * u2;
                float t0 = Aw * af.y;
                acc1 = fmaf(t0, u,  acc1);
                acc2 = fmaf(t0, u2, acc2);
                acc3 = fmaf(t0, u4, acc3);
            }
        }
    }

    if (any) {
        int orig = perm[p];
        atomicAdd(&out[3*orig+0], acc1 * n1);
        atomicAdd(&out[3*orig+1], acc2 * n2);
        atomicAdd(&out[3*orig+2], acc3 * n3);
    }
}

extern "C" void kernel_launch(void* const* d_in, const int* in_sizes, int n_in,
                              void* d_out, int out_size, void* d_ws, size_t ws_size,
                              hipStream_t stream)
{
    const float* rho     = (const float*)d_in[0];
    const float* gamma   = (const float*)d_in[1];
    const float* coords  = (const float*)d_in[2];
    const float* weights = (const float*)d_in[3];
    float*       out     = (float*)d_out;
    const int    n       = in_sizes[0];
    const int    nt      = n / TSZ;              // 256 tiles

    const double C2d  = pow(6.0 * M_PI * M_PI, 2.0 / 3.0) * (6.0 * 2.0 / (160.0 * M_PI));
    const double Kd   = 0.3 * pow(3.0 * M_PI * M_PI, 2.0 / 3.0);
    const float  nrm1 = (float)pow(1.5, 1.5);
    const float  nrm2 = (float)pow(2.0, 1.5);
    const float  nrm3 = (float)pow(3.0, 1.5);

    // workspace ~488 KB (proven size range)
    char* w = (char*)d_ws;
    float4*         XYZQ   = (float4*)w;          w += (size_t)n * sizeof(float4);   // 256K
    float2*         AF     = (float2*)w;          w += (size_t)n * sizeof(float2);   // 128K
    unsigned short* perm   = (unsigned short*)w;  w += (size_t)n * sizeof(short);    // 32K
    unsigned short* cellid = (unsigned short*)w;  w += (size_t)n * sizeof(short);    // 32K
    int*            cursor = (int*)w;             w += (size_t)NCELL * sizeof(int);  // 32K
    float*          tiles  = (float*)w;           w += (size_t)nt * 8 * sizeof(float);

    hipMemsetAsync(out, 0, (size_t)out_size * sizeof(float), stream);

    k_cells  <<<1, 1024, 0, stream>>>(rho, gamma, coords, cellid, cursor,
                                      n, (float)C2d, (float)Kd);
    k_scatter<<<(n + 255) / 256, 256, 0, stream>>>(rho, gamma, coords, weights,
                                                   cellid, cursor, XYZQ, AF, perm,
                                                   n, (float)C2d, (float)Kd);
    k_bounds <<<nt, TSZ, 0, stream>>>(XYZQ, AF, tiles);

    dim3 grid(nt / 4, SPLIT);
    k_main   <<<grid, 256, 0, stream>>>(XYZQ, AF, perm, tiles, out, nt,
                                        nrm1, nrm2, nrm3);
}

// Round 9
// 159.014 us; speedup vs baseline: 1.0232x; 1.0232x over previous
//
#include <hip/hip_runtime.h>
#include <math.h>

#ifndef M_PI
#define M_PI 3.14159265358979323846
#endif

constexpr int   NMORT = 4096;       // 16^3 morton cells, side 2.0, world [-16,16)
constexpr int   NBUCK = 4;          // tightness buckets on A = a*log2e
constexpr int   NCELL = NBUCK * NMORT;
constexpr int   TSZI  = 64;         // i-points per wave
constexpr int   TSZJ  = 32;         // j-points per gated tile
constexpr int   SPLIT = 16;         // j slices (blockIdx.y)
constexpr float CUT   = 24.0f;      // skip when (Aj+Bi)s >= CUT+log2 fj; err<=16384*5.2*2^-24~5e-3

// y[i,c] = norms[c] * sum_j exp(-(a_j + b_ic)||xi-xj||^2) f_j ; b_i = {a/2, a, 2a}
// u = exp2(-(Ai/2)s), Aw = exp2(-Aj*s) -> w = {Aw u, Aw u^2, Aw u^4}

__device__ __forceinline__ int expand4(int v) {
    return (v & 1) | ((v & 2) << 2) | ((v & 4) << 4) | ((v & 8) << 6);
}

__device__ __forceinline__ float compA(float rho_, float gam, float C2, float Kttf) {
    const float LOG2E = 1.4426950408889634f;
    const float PI_F  = 3.14159265358979f;
    float r  = rho_ + 1e-8f;
    float sc = PI_F * powf(0.5f * r, 2.0f / 3.0f);
    float xq = (gam / (8.0f * r)) / (Kttf * powf(r, 5.0f / 3.0f));
    return LOG2E * sc * (2.0f + C2 * xq);      // a * log2(e) > 0
}

__device__ __forceinline__ int cellkey(float x, float y, float z, float A) {
    int cx = min(15, max(0, (int)floorf((x + 16.f) * 0.5f)));
    int cy = min(15, max(0, (int)floorf((y + 16.f) * 0.5f)));
    int cz = min(15, max(0, (int)floorf((z + 16.f) * 0.5f)));
    int m  = expand4(cx) | (expand4(cy) << 1) | (expand4(cz) << 2);
    int b  = (A >= 6.0f) ? 3 : (A >= 3.0f) ? 2 : (A >= 1.5f) ? 1 : 0;
    return b * NMORT + m;
}

// K1: histogram (multi-block, global atomics)
__global__ __launch_bounds__(256)
void k_hist(const float* __restrict__ rho, const float* __restrict__ gamma,
            const float* __restrict__ coords, int* __restrict__ hist,
            int n, float C2, float Kttf)
{
    int i = blockIdx.x * 256 + threadIdx.x;
    if (i >= n) return;
    float A = compA(rho[i], gamma[i], C2, Kttf);
    atomicAdd(&hist[cellkey(coords[3*i], coords[3*i+1], coords[3*i+2], A)], 1);
}

// K2: in-place exclusive scan of hist (one block, 16 bins/thread)
__global__ __launch_bounds__(1024)
void k_scan(int* __restrict__ hist)
{
    __shared__ int ssum[1024];
    const int t = threadIdx.x, base = t * 16;
    int h[16], s = 0;
    #pragma unroll
    for (int k = 0; k < 16; ++k) { h[k] = hist[base + k]; s += h[k]; }
    ssum[t] = s;
    __syncthreads();
    for (int off = 1; off < 1024; off <<= 1) {
        int v = (t >= off) ? ssum[t - off] : 0;
        __syncthreads();
        ssum[t] += v;
        __syncthreads();
    }
    int excl = ssum[t] - s;
    #pragma unroll
    for (int k = 0; k < 16; ++k) { hist[base + k] = excl; excl += h[k]; }
}

// K3: scatter into sorted order + per-point precompute (hist = cursor)
__global__ __launch_bounds__(256)
void k_scatter(const float* __restrict__ rho, const float* __restrict__ gamma,
               const float* __restrict__ coords, const float* __restrict__ weights,
               int* __restrict__ cursor, float4* __restrict__ XYZQ,
               float2* __restrict__ AF, unsigned short* __restrict__ perm,
               int n, float C2, float Kttf)
{
    int i = blockIdx.x * 256 + threadIdx.x;
    if (i >= n) return;
    float A = compA(rho[i], gamma[i], C2, Kttf);
    float x = coords[3*i], y = coords[3*i+1], z = coords[3*i+2];
    int pos = atomicAdd(&cursor[cellkey(x, y, z, A)], 1);
    XYZQ[pos] = make_float4(x, y, z, x*x + y*y + z*z);
    AF[pos]   = make_float2(A, weights[i] * rho[i]);
    perm[pos] = (unsigned short)i;
}

// K4: per-32-point j-tile bounds {minx,miny,minz,maxx, maxy,maxz, Amin, Lmax}
__global__ __launch_bounds__(64)
void k_bounds(const float4* __restrict__ XYZQ, const float2* __restrict__ AF,
              float* __restrict__ tiles)
{
    int p  = blockIdx.x * 64 + threadIdx.x;
    int jt = blockIdx.x * 2 + (threadIdx.x >> 5);
    float4 v  = XYZQ[p];
    float2 af = AF[p];
    float lf = log2f(fmaxf(af.y, 1e-30f));
    float mnx=v.x, mny=v.y, mnz=v.z, mxx=v.x, mxy=v.y, mxz=v.z, mA=af.x, mL=lf;
    for (int d = 1; d < 32; d <<= 1) {
        mnx = fminf(mnx, __shfl_xor(mnx, d, 32));
        mny = fminf(mny, __shfl_xor(mny, d, 32));
        mnz = fminf(mnz, __shfl_xor(mnz, d, 32));
        mxx = fmaxf(mxx, __shfl_xor(mxx, d, 32));
        mxy = fmaxf(mxy, __shfl_xor(mxy, d, 32));
        mxz = fmaxf(mxz, __shfl_xor(mxz, d, 32));
        mA  = fminf(mA,  __shfl_xor(mA,  d, 32));
        mL  = fmaxf(mL,  __shfl_xor(mL,  d, 32));
    }
    if ((threadIdx.x & 31) == 0) {
        float* tb = tiles + jt * 8;
        tb[0]=mnx; tb[1]=mny; tb[2]=mnz; tb[3]=mxx;
        tb[4]=mxy; tb[5]=mxz; tb[6]=mA;  tb[7]=mL;
    }
}

// K5: main — j-tile AABB gate + per-j wave-vote exp skip
__global__ __launch_bounds__(256)
void k_main(const float4* __restrict__ XYZQ, const float2* __restrict__ AF,
            const unsigned short* __restrict__ perm, const float* __restrict__ tiles,
            float* __restrict__ out, int ntj,
            float n1, float n2, float n3)
{
    const int wave = threadIdx.x >> 6;
    const int lane = threadIdx.x & 63;
    const int it   = blockIdx.x * 4 + wave;      // i-tile (64 pts) index
    const int p    = it * TSZI + lane;

    float4 me  = XYZQ[p];
    float2 maf = AF[p];
    const float xi = me.x, yi = me.y, zi = me.z, qi = me.w;
    const float m2 = 0.5f * maf.x;               // Bi = (a_i/2) log2e
    const float mx2 = -2.0f * xi, my2 = -2.0f * yi, mz2 = -2.0f * zi;

    // wave AABB + Bmin (64-lane butterfly)
    float mnx=xi, mny=yi, mnz=zi, mxx=xi, mxy=yi, mxz=zi, mB=m2;
    for (int d = 1; d < 64; d <<= 1) {
        mnx = fminf(mnx, __shfl_xor(mnx, d));
        mny = fminf(mny, __shfl_xor(mny, d));
        mnz = fminf(mnz, __shfl_xor(mnz, d));
        mxx = fmaxf(mxx, __shfl_xor(mxx, d));
        mxy = fmaxf(mxy, __shfl_xor(mxy, d));
        mxz = fmaxf(mxz, __shfl_xor(mxz, d));
        mB  = fminf(mB,  __shfl_xor(mB,  d));
    }

    float acc1 = 0.f, acc2 = 0.f, acc3 = 0.f;
    bool any = false;

    const int tps = ntj / SPLIT;                 // j-tiles per slice
    for (int k = 0; k < tps; ++k) {
        int jt = blockIdx.y + k * SPLIT;         // strided -> load balance
        const float* tb = tiles + jt * 8;
        float gx = fmaxf(0.f, fmaxf(tb[0] - mxx, mnx - tb[3]));
        float gy = fmaxf(0.f, fmaxf(tb[1] - mxy, mny - tb[4]));
        float gz = fmaxf(0.f, fmaxf(tb[2] - mxz, mnz - tb[5]));
        float d2 = gx*gx + gy*gy + gz*gz;
        float ctile = CUT + tb[7];
        if (d2 * (tb[6] + mB) > ctile) continue;
        any = true;
        int jb = jt * TSZJ;
        #pragma unroll 4
        for (int jj = 0; jj < TSZJ; ++jj) {
            float4 J  = XYZQ[jb + jj];           // uniform addr -> s_load
            float2 af = AF[jb + jj];
            float s  = fmaf(J.x, mx2, fmaf(J.y, my2, fmaf(J.z, mz2, J.w + qi)));
            float tA = af.x * s;                 // Aj*s (= exp arg)
            float m  = fmaf(s, mB, tA);          // (Aj+Bmin)*s
            if (__any(m < ctile)) {
                float Aw = __builtin_amdgcn_exp2f(-tA);
                float u  = __builtin_amdgcn_exp2f(-(m2 * s));
                float u2 = u * u, u4 = u2 * u2;
                float t0 = Aw * af.y;
                acc1 = fmaf(t0, u,  acc1);
                acc2 = fmaf(t0, u2, acc2);
                acc3 = fmaf(t0, u4, acc3);
            }
        }
    }

    if (any) {
        int orig = perm[p];
        atomicAdd(&out[3*orig+0], acc1 * n1);
        atomicAdd(&out[3*orig+1], acc2 * n2);
        atomicAdd(&out[3*orig+2], acc3 * n3);
    }
}

extern "C" void kernel_launch(void* const* d_in, const int* in_sizes, int n_in,
                              void* d_out, int out_size, void* d_ws, size_t ws_size,
                              hipStream_t stream)
{
    const float* rho     = (const float*)d_in[0];
    const float* gamma   = (const float*)d_in[1];
    const float* coords  = (const float*)d_in[2];
    const float* weights = (const float*)d_in[3];
    float*       out     = (float*)d_out;
    const int    n       = in_sizes[0];
    const int    nti     = n / TSZI;             // 256 i-tiles
    const int    ntj     = n / TSZJ;             // 512 j-tiles

    const double C2d  = pow(6.0 * M_PI * M_PI, 2.0 / 3.0) * (6.0 * 2.0 / (160.0 * M_PI));
    const double Kd   = 0.3 * pow(3.0 * M_PI * M_PI, 2.0 / 3.0);
    const float  nrm1 = (float)pow(1.5, 1.5);
    const float  nrm2 = (float)pow(2.0, 1.5);
    const float  nrm3 = (float)pow(3.0, 1.5);

    // workspace ~496 KB (within proven range)
    char* w = (char*)d_ws;
    float4*         XYZQ = (float4*)w;          w += (size_t)n * sizeof(float4);    // 256K
    float2*         AF   = (float2*)w;          w += (size_t)n * sizeof(float2);    // 128K
    unsigned short* perm = (unsigned short*)w;  w += (size_t)n * sizeof(short);     // 32K
    int*            hist = (int*)w;             w += (size_t)NCELL * sizeof(int);   // 64K
    float*          tiles= (float*)w;           w += (size_t)ntj * 8 * sizeof(float);// 16K

    hipMemsetAsync(hist, 0, NCELL * sizeof(int), stream);
    hipMemsetAsync(out, 0, (size_t)out_size * sizeof(float), stream);

    k_hist   <<<(n + 255) / 256, 256, 0, stream>>>(rho, gamma, coords, hist,
                                                   n, (float)C2d, (float)Kd);
    k_scan   <<<1, 1024, 0, stream>>>(hist);
    k_scatter<<<(n + 255) / 256, 256, 0, stream>>>(rho, gamma, coords, weights,
                                                   hist, XYZQ, AF, perm,
                                                   n, (float)C2d, (float)Kd);
    k_bounds <<<ntj / 2, 64, 0, stream>>>(XYZQ, AF, tiles);

    dim3 grid(nti / 4, SPLIT);
    k_main   <<<grid, 256, 0, stream>>>(XYZQ, AF, perm, tiles, out, ntj,
                                        nrm1, nrm2, nrm3);
}